// Round 7
// baseline (291.553 us; speedup 1.0000x reference)
//
#include <hip/hip_runtime.h>
#include <math.h>

#define BB 8
#define CC 256
#define KK 19
#define HW 16384
#define HW4 4096            // HW / 4 (float4 units)

#define CHUNK4 32           // float4 per hw-chunk = 128 floats
#define NS (HW4 / CHUNK4)   // 128 chunks per batch

// ---- K1 history ----
// r1: thread-per-channel, map in LDS: 93 us. LDS-issue-bound + spill.
// r2/r3: more ch/thread -> compiler pinned 64 VGPRs -> acc in scratch ->
//     0.8-2.5 GB scratch traffic. Lesson: design INSIDE 64 VGPRs.
// r4: map->SGPR asm + feature->LDS via global_load_lds + k-split. Compile
//     fail (divergent pointer for "s" constraint).
// r5: readfirstlane'd bases. VGPR=44, zero scratch, but 100 us: per-j
//     `s_waitcnt lgkmcnt(0)` inside the asm full-drained SMEM+DS 64x/wave.
// r6: constant-AS pointers -> compiler-scheduled s_load_dwordx4. K1 < 79 us
//     (dropped out of top-5; est 55-65). Remaining model: DS pipe ~20 us/CU
//     because the 4-way k-split makes ALL 4 waves read the ENTIRE feature
//     tile (4x read amplification), + SMEM/DS lgkmcnt mixing.
// r7 (this): 2D wave split (kh = w&1 over k-halves, ch = w>>1 over row
//     halves). Per thread: 1 feature ds_read/j (was 2), 10 acc (unchanged),
//     40 FMAs/j (unchanged). DS amplification 4x -> 2x. Cross-wave combine
//     phase deleted: each (k,c) owned by one wave -> direct coalesced part
//     store (k9 dup computed by kh=1 but stored only by kh=0).

typedef float f32x4 __attribute__((ext_vector_type(4)));

#define AS1C(p) ((const __attribute__((address_space(1))) void*)(p))
#define AS3(p)  ((__attribute__((address_space(3))) void*)(p))

// Constant-AS vector pointer: uniform address + read-only memory -> s_load.
typedef const __attribute__((address_space(4))) f32x4* cvec4p;
#define CVEC4(p) ((cvec4p)(unsigned long long)(p))

// Per-wave uniform pointer: readfirstlane both halves. Safe because the
// value is wave-uniform by construction (w = t>>6 is constant in a wave).
static __device__ __forceinline__ const float* uniform_ptr(const float* p) {
    unsigned long long u = (unsigned long long)p;
    unsigned lo = __builtin_amdgcn_readfirstlane((unsigned)u);
    unsigned hi = __builtin_amdgcn_readfirstlane((unsigned)(u >> 32));
    return (const float*)(((unsigned long long)hi << 32) | lo);
}

#define FMAC(AV, MV, FV)                                                 \
    AV += FV.x * MV.x; AV += FV.y * MV.y; AV += FV.z * MV.z; AV += FV.w * MV.w;

__global__ __launch_bounds__(256) void CGM_k1_contract(
    const float* __restrict__ feature,
    const float* __restrict__ map_,
    float* __restrict__ att,        // fallback target (pre-zeroed)
    float* __restrict__ part)       // [KK][BB][NS][CC] partials, or nullptr
{
    const int bI   = blockIdx.x;            // ((b*NS + s) << 1) | half
    const int half = bI & 1;                // channel half: c in [half*128, +128)
    const int s    = (bI >> 1) & (NS - 1);
    const int b    = bI >> 8;
    const int t    = threadIdx.x;
    const int l    = t & 63;
    const int w    = t >> 6;                // wave id
    const int kh   = w & 1;                 // k-half: k in [kh*9, kh*9+9]
    const int ch   = w >> 1;                // row half: rows ch*64 + l
    const int r    = ch * 64 + l;           // this thread's tile row

    // 2 x 16 KB: tile = [128 ch][8 float4], double-buffered.
    __shared__ float4 buf[2][1024];

    const int klo = kh * 9;                 // 0 or 9; rows klo..klo+9
    // Wave-uniform map base (k row klo) for this chunk.
    const float* mw_raw = map_ + (size_t)b * KK * HW + (size_t)klo * HW
                        + (size_t)s * (CHUNK4 * 4);
    const float* mw = uniform_ptr(mw_raw);

    // Constant-AS row pointers -> compiler-scheduled s_load_dwordx4 off one
    // base with immediate offsets (ki*HW*4 = ki*64KB <= 576KB < 21-bit imm).
    cvec4p cm0 = CVEC4(mw);
    cvec4p cm1 = CVEC4(mw + 1 * (size_t)HW);
    cvec4p cm2 = CVEC4(mw + 2 * (size_t)HW);
    cvec4p cm3 = CVEC4(mw + 3 * (size_t)HW);
    cvec4p cm4 = CVEC4(mw + 4 * (size_t)HW);
    cvec4p cm5 = CVEC4(mw + 5 * (size_t)HW);
    cvec4p cm6 = CVEC4(mw + 6 * (size_t)HW);
    cvec4p cm7 = CVEC4(mw + 7 * (size_t)HW);
    cvec4p cm8 = CVEC4(mw + 8 * (size_t)HW);
    cvec4p cm9 = CVEC4(mw + 9 * (size_t)HW);

    const float4* fbase = (const float4*)feature
                        + ((size_t)b * CC + half * 128) * HW4 + s * CHUNK4;

    // Stage tile JT into buf[BUFIDX]: linear LDS dest (wave-uniform base +
    // lane*16) + inverse-swizzled global source. 4 issues/thread, VGPR-free.
#define STAGE(BUFIDX, JT) do {                                           \
    _Pragma("unroll")                                                    \
    for (int q = 0; q < 4; ++q) {                                        \
        const int slot = q * 256 + t;                                    \
        const int chs  = slot >> 3;                                      \
        const int js   = slot & 7;                                       \
        const float4* g = fbase + (size_t)chs * HW4                      \
                        + (JT) * 8 + (js ^ (chs & 7));                   \
        __builtin_amdgcn_global_load_lds(AS1C(g),                        \
            AS3(&buf[BUFIDX][slot]), 16, 0, 0);                          \
    }                                                                    \
} while (0)

    float A0 = 0.f, A1 = 0.f, A2 = 0.f, A3 = 0.f, A4 = 0.f;
    float A5 = 0.f, A6 = 0.f, A7 = 0.f, A8 = 0.f, A9 = 0.f;

    // Compute tile JT out of buf[BUFIDX]: per j, 10 s_load_dwordx4 map rows
    // feed ONE swizzled ds_read_b128 (row r) and 40 FMAs.
    // Swizzle check: LDS[chs][js] = G[chs][js^(chs&7)] (staged), read
    // LDS[r][j^(r&7)] = G[r][j].
#define COMPUTE(BUFIDX, JT) do {                                         \
    const float4* bc = buf[BUFIDX];                                      \
    _Pragma("unroll")                                                    \
    for (int j = 0; j < 8; ++j) {                                        \
        const int jj = (JT) * 8 + j;                                     \
        const f32x4 m0 = cm0[jj];                                        \
        const f32x4 m1 = cm1[jj];                                        \
        const f32x4 m2 = cm2[jj];                                        \
        const f32x4 m3 = cm3[jj];                                        \
        const f32x4 m4 = cm4[jj];                                        \
        const f32x4 m5 = cm5[jj];                                        \
        const f32x4 m6 = cm6[jj];                                        \
        const f32x4 m7 = cm7[jj];                                        \
        const f32x4 m8 = cm8[jj];                                        \
        const f32x4 m9 = cm9[jj];                                        \
        const float4 f = bc[(size_t)r * 8 + (j ^ (r & 7))];              \
        FMAC(A0, m0, f) FMAC(A1, m1, f) FMAC(A2, m2, f)                  \
        FMAC(A3, m3, f) FMAC(A4, m4, f) FMAC(A5, m5, f)                  \
        FMAC(A6, m6, f) FMAC(A7, m7, f) FMAC(A8, m8, f)                  \
        FMAC(A9, m9, f)                                                  \
    }                                                                    \
} while (0)

    // 2-phase pipeline over the 4 j-tiles. STAGE(next) is issued before
    // COMPUTE(cur); __syncthreads' implicit vmcnt(0) drain comes after the
    // compute, so the staging loads fly underneath it.
    STAGE(0, 0); __syncthreads();
    STAGE(1, 1); COMPUTE(0, 0); __syncthreads();
    STAGE(0, 2); COMPUTE(1, 1); __syncthreads();
    STAGE(1, 3); COMPUTE(0, 2); __syncthreads();
    COMPUTE(1, 3);

#undef STAGE
#undef COMPUTE

    // Direct store: each (k, c) owned by exactly one wave. k9 is computed
    // by BOTH k-halves (kh=1's ki=0) but stored only by kh=0.
    const int cbase = half * 128 + r;
    if (part) {
        // part[k][b][s][c]: one coalesced 256 B wave store per k.
#define STK(KI, AV) if ((KI) > 0 || kh == 0) {                           \
        float* d = part + ((size_t)((klo + (KI)) * BB + b) * NS + s) * CC \
                 + cbase;                                                \
        *d = AV; }
        STK(0, A0) STK(1, A1) STK(2, A2) STK(3, A3) STK(4, A4)
        STK(5, A5) STK(6, A6) STK(7, A7) STK(8, A8) STK(9, A9)
#undef STK
    } else {
        // Fallback: fp32 atomics into pre-zeroed att.
#define STK(KI, AV) if ((KI) > 0 || kh == 0) {                           \
        atomicAdd(&att[(size_t)(b * CC + cbase) * KK + klo + (KI)], AV); }
        STK(0, A0) STK(1, A1) STK(2, A2) STK(3, A3) STK(4, A4)
        STK(5, A5) STK(6, A6) STK(7, A7) STK(8, A8) STK(9, A9)
#undef STK
    }
}

// ---- K1b: fold the NS=128 hw-chunk partials into att (validated r1-r6). ----
__global__ __launch_bounds__(256) void CGM_k1b_reduce(
    const float* __restrict__ part,
    float* __restrict__ att)
{
    const int bk = blockIdx.x;      // b*KK + k
    const int b  = bk / KK;
    const int k  = bk - b * KK;
    const int t  = threadIdx.x;
    const int q  = t & 63;          // float4 column: channels 4q..4q+3
    const int sg = t >> 6;          // s quarter: 32 rows

    const float4* p4 = (const float4*)(part + (size_t)(k * BB + b) * NS * CC)
                     + (size_t)(sg * 32) * 64 + q;

    float4 a0 = {0.f, 0.f, 0.f, 0.f}, a1 = a0, a2 = a0, a3 = a0;
#pragma unroll 2
    for (int i = 0; i < 32; i += 4) {
        const float4 v0 = p4[(size_t)(i + 0) * 64];
        const float4 v1 = p4[(size_t)(i + 1) * 64];
        const float4 v2 = p4[(size_t)(i + 2) * 64];
        const float4 v3 = p4[(size_t)(i + 3) * 64];
        a0.x += v0.x; a0.y += v0.y; a0.z += v0.z; a0.w += v0.w;
        a1.x += v1.x; a1.y += v1.y; a1.z += v1.z; a1.w += v1.w;
        a2.x += v2.x; a2.y += v2.y; a2.z += v2.z; a2.w += v2.w;
        a3.x += v3.x; a3.y += v3.y; a3.z += v3.z; a3.w += v3.w;
    }
    float4 r;
    r.x = (a0.x + a1.x) + (a2.x + a3.x);
    r.y = (a0.y + a1.y) + (a2.y + a3.y);
    r.z = (a0.z + a1.z) + (a2.z + a3.z);
    r.w = (a0.w + a1.w) + (a2.w + a3.w);

    __shared__ float4 red[4][64];
    red[sg][q] = r;
    __syncthreads();
    if (t < 64) {
        const float4 u0 = red[0][q], u1 = red[1][q], u2 = red[2][q], u3 = red[3][q];
        float4 o;
        o.x = (u0.x + u1.x) + (u2.x + u3.x);
        o.y = (u0.y + u1.y) + (u2.y + u3.y);
        o.z = (u0.z + u1.z) + (u2.z + u3.z);
        o.w = (u0.w + u1.w) + (u2.w + u3.w);
        float* d = att + ((size_t)b * CC + 4 * q) * KK + k;
        d[0 * KK] = o.x;
        d[1 * KK] = o.y;
        d[2 * KK] = o.z;
        d[3 * KK] = o.w;
    }
}

// ---- K2: gate + apply (frozen since round 2) ----
#define S2 8                 // hw splits
#define CT2 16               // channels per block
#define CHUNK24 (HW4 / S2)   // 512 float4

#define FOR_K(OP) OP(0) OP(1) OP(2) OP(3) OP(4) OP(5) OP(6) OP(7) OP(8) OP(9) \
                  OP(10) OP(11) OP(12) OP(13) OP(14) OP(15) OP(16) OP(17) OP(18)

__global__ __launch_bounds__(256) void CGM_k2_apply(
    const float* __restrict__ feature,
    const float* __restrict__ gamma,
    const float* __restrict__ att,
    float* __restrict__ out)
{
    const int bI = blockIdx.x;
    const int ct = bI & 15;
    const int s  = (bI >> 4) & (S2 - 1);
    const int b  = bI >> 7;
    const int t  = threadIdx.x;
    const int c0 = ct * CT2;

    __shared__ float sgk[CT2 * KK];
    __shared__ float scale[CT2];

    // NOTE: CT2*KK = 304 > 256 threads — MUST be a strided loop, not `if`.
    for (int idx = t; idx < CT2 * KK; idx += 256) {
        const int c = idx / KK;
        const int k = idx - c * KK;
        const float a = att[(size_t)(b * CC + c0 + c) * KK + k];
        const float sig = 1.f / (1.f + __expf(-a));
        sgk[idx] = sig * gamma[k];
    }
    __syncthreads();

    if (t < CT2) {
        float ssum = 0.f;
#define ADDK(K) ssum += sgk[t * KK + (K)];
        FOR_K(ADDK)
#undef ADDK
        scale[t] = 1.f + ssum;
    }
    __syncthreads();

    const float4* f4 = (const float4*)feature + (size_t)(b * CC + c0) * HW4;
    float4*       o4 = (float4*)out           + (size_t)(b * CC + c0) * HW4;
    const int ibase = s * CHUNK24;
#pragma unroll
    for (int c = 0; c < CT2; ++c) {
        const float sc = scale[c];
#pragma unroll
        for (int r = 0; r < CHUNK24 / 256; ++r) {   // 2 iterations
            const int i = ibase + r * 256 + t;
            const float4 f = f4[(size_t)c * HW4 + i];
            float4 o;
            o.x = f.x * sc;
            o.y = f.y * sc;
            o.z = f.z * sc;
            o.w = f.w * sc;
            o4[(size_t)c * HW4 + i] = o;
        }
    }
}

extern "C" void kernel_launch(void* const* d_in, const int* in_sizes, int n_in,
                              void* d_out, int out_size, void* d_ws, size_t ws_size,
                              hipStream_t stream) {
    const float* feature = (const float*)d_in[0];
    const float* map_    = (const float*)d_in[1];
    const float* gamma   = (const float*)d_in[2];
    float* out           = (float*)d_out;
    float* att           = (float*)d_ws;   // BB*CC*KK*4 = 155,648 B

    const size_t att_bytes  = (size_t)BB * CC * KK * sizeof(float);
    const size_t part_off   = (att_bytes + 255) & ~(size_t)255;
    const size_t part_bytes = (size_t)KK * BB * NS * CC * sizeof(float); // 19,922,944 B
    const bool   split      = ws_size >= part_off + part_bytes;
    float* part = split ? (float*)((char*)d_ws + part_off) : nullptr;

    if (!split) {
        // att is re-poisoned to 0xAA before every launch — atomic fallback
        // needs it zeroed (hipMemsetAsync on stream is graph-capture safe).
        hipMemsetAsync(att, 0, att_bytes, stream);
    }

    const int grid1 = BB * NS * 2;            // 2048 (channel halves)
    CGM_k1_contract<<<grid1, 256, 0, stream>>>(feature, map_, att, part);

    if (split) {
        CGM_k1b_reduce<<<BB * KK, 256, 0, stream>>>(part, att);
    }

    const int grid2 = BB * S2 * (CC / CT2);   // 1024
    CGM_k2_apply<<<grid2, 256, 0, stream>>>(feature, gamma, att, out);
}